// Round 10
// baseline (183.650 us; speedup 1.0000x reference)
//
#include <hip/hip_runtime.h>
#include <stdint.h>
#include <math.h>

#define T_SEQ 2048
#define NHEAD 16
#define WIN 256

typedef unsigned short u16;
typedef __attribute__((ext_vector_type(8))) short short8;
typedef __attribute__((ext_vector_type(4))) float f32x4;

typedef const __attribute__((address_space(1))) void* gas_ptr;
typedef __attribute__((address_space(3))) void* las_ptr;

__device__ __forceinline__ u16 f2bf(float f) {
  uint32_t u = __builtin_bit_cast(uint32_t, f);
  u += 0x7fffu + ((u >> 16) & 1u);
  return (u16)(u >> 16);
}
__device__ __forceinline__ float bf2f(u16 v) {
  return __builtin_bit_cast(float, ((uint32_t)v) << 16);
}
__device__ __forceinline__ void g2l16(const u16* g, u16* l) {
  __builtin_amdgcn_global_load_lds((gas_ptr)g, (las_ptr)l, 16, 0, 0);
}

// ---------------- fp32 -> bf16 cast (vectorized) ----------------
__global__ __launch_bounds__(256) void cast_bf16_k(const float* __restrict__ in,
                                                   u16* __restrict__ out, int n4) {
  int i = blockIdx.x * 256 + threadIdx.x;
  if (i >= n4) return;
  const float4 v = reinterpret_cast<const float4*>(in)[i];
  union { u16 h[4]; uint64_t q; } o;
  o.h[0] = f2bf(v.x); o.h[1] = f2bf(v.y); o.h[2] = f2bf(v.z); o.h[3] = f2bf(v.w);
  reinterpret_cast<uint64_t*>(out)[i] = o.q;
}

// ---------------- NT GEMM: C[M][N] = A[M][K] * B[N][K]^T ----------------
// 128x128 tile, BK=32, 4 waves (2x2), 4x4 16x16x32 MFMA frags per wave.
// Round-10: 3-buffer LDS pipeline, tile t+2 staged at iter t; per-wave
// counted s_waitcnt vmcnt(4) + RAW s_barrier (no vmcnt(0) drain) so loads
// stay in flight across barriers (T4). Loads get ~2 iterations to land.
template <typename OUT_T>
__global__ __launch_bounds__(256) void gemm_nt(const u16* __restrict__ A,
                                               const u16* __restrict__ B,
                                               OUT_T* __restrict__ C,
                                               int M, int N, int K) {
  __shared__ u16 lA[3][4096];  // 3 x 8KB per operand = 48KB total
  __shared__ u16 lB[3][4096];
  const int tid = threadIdx.x;
  const int lane = tid & 63;
  const int wave = tid >> 6;
  const int r = lane & 15, g = lane >> 4;
  const int wr = wave >> 1, wc = wave & 1;

  // XCD remap: bid%8 = xcd; xcd owns bn in [xcd*bnpx, (xcd+1)*bnpx), bm 0..
  const int nbn = N >> 7;            // 128-wide tiles; nbn % 8 == 0 required
  const int bnpx = nbn >> 3;
  const int bid = blockIdx.x;
  const int xcd = bid & 7, ii = bid >> 3;
  const int bn = xcd * bnpx + (ii % bnpx);
  const int bm = ii / bnpx;

  const u16* Abase = A + (size_t)bm * 128 * K;
  const u16* Bbase = B + (size_t)bn * 128 * K;

  f32x4 acc[4][4];
#pragma unroll
  for (int m = 0; m < 4; m++)
#pragma unroll
    for (int n = 0; n < 4; n++) acc[m][n] = (f32x4){0.f, 0.f, 0.f, 0.f};

  // staging: 512 16B-chunks per operand tile; chunk c -> row c>>2, col-chunk
  // c&3, source column pre-swizzled by row&3 (LDS dest stays linear).
  const int c0 = tid, c1 = 256 + tid;
  const int row0 = c0 >> 2, row1 = c1 >> 2;
  const int sw0 = ((c0 & 3) ^ (row0 & 3)) * 8;
  const int sw1 = ((c1 & 3) ^ (row1 & 3)) * 8;
  const int ldsb = wave * 512;  // wave-uniform LDS elem base (lane*16B implicit)

  auto stage = [&](int k0, int b) {  // 4 global_load_lds per wave
    g2l16(Abase + (size_t)row0 * K + k0 + sw0, &lA[b][ldsb]);
    g2l16(Abase + (size_t)row1 * K + k0 + sw1, &lA[b][2048 + ldsb]);
    g2l16(Bbase + (size_t)row0 * K + k0 + sw0, &lB[b][ldsb]);
    g2l16(Bbase + (size_t)row1 * K + k0 + sw1, &lB[b][2048 + ldsb]);
  };

  const int nt = K >> 5;
  stage(0, 0);
  if (nt > 1) stage(32, 1);
  int cur = 0, pre = 2;  // compute buf t%3; stage target (t+2)%3

  const int rsw = (r & 3);  // read-side swizzle key (row & 3 == r & 3)
  for (int t = 0; t < nt; ++t) {
    // wait own tile-t loads (4/tile in flight per later tile), never full drain
    if (t + 1 < nt) asm volatile("s_waitcnt vmcnt(4)" ::: "memory");
    else            asm volatile("s_waitcnt vmcnt(0)" ::: "memory");
    __builtin_amdgcn_s_barrier();   // all waves' tile-t loads visible
    if (t + 2 < nt) stage((t + 2) * 32, pre);  // overwrites buf read at t-1

    const u16* la = lA[cur];
    const u16* lb = lB[cur];
    short8 af[4], bfr[4];
#pragma unroll
    for (int m = 0; m < 4; m++)
      af[m] = *reinterpret_cast<const short8*>(
          &la[(wr * 64 + m * 16 + r) * 32 + ((g ^ rsw) * 8)]);
#pragma unroll
    for (int n = 0; n < 4; n++)
      bfr[n] = *reinterpret_cast<const short8*>(
          &lb[(wc * 64 + n * 16 + r) * 32 + ((g ^ rsw) * 8)]);
#pragma unroll
    for (int m = 0; m < 4; m++)
#pragma unroll
      for (int n = 0; n < 4; n++)
        acc[m][n] = __builtin_amdgcn_mfma_f32_16x16x32_bf16(af[m], bfr[n], acc[m][n], 0, 0, 0);
    // retire this iter's ds_reads before next barrier (cross-wave overwrite safety)
    asm volatile("s_waitcnt lgkmcnt(0)" ::: "memory");
    cur = (cur == 2) ? 0 : cur + 1;
    pre = (pre == 2) ? 0 : pre + 1;
  }

#pragma unroll
  for (int m = 0; m < 4; m++) {
    const int row = bm * 128 + wr * 64 + m * 16 + g * 4;
#pragma unroll
    for (int n = 0; n < 4; n++) {
      const int col = bn * 128 + wc * 64 + n * 16 + r;
#pragma unroll
      for (int j = 0; j < 4; j++) {
        float v = acc[m][n][j];
        if constexpr (sizeof(OUT_T) == 2)
          C[(size_t)(row + j) * N + col] = f2bf(v);
        else
          C[(size_t)(row + j) * N + col] = v;
      }
    }
  }
}

// ---------------- RoPE + split qkv -> Q,K (B,H,T,Dh) bf16 ----------------
__global__ __launch_bounds__(256) void rope_qk(const u16* __restrict__ qkv,
                                               u16* __restrict__ Qb,
                                               u16* __restrict__ Kb) {
  int idx = blockIdx.x * 256 + threadIdx.x;  // B*H*T*32 = 2M threads
  int d = idx & 31;
  int t = (idx >> 5) & (T_SEQ - 1);
  int h = (idx >> 16) & (NHEAD - 1);
  int b = idx >> 20;
  size_t mrow = ((size_t)(b * T_SEQ + t)) * 3072;
  int hd = h * 64 + d;
  float q1 = bf2f(qkv[mrow + hd]);
  float q2 = bf2f(qkv[mrow + hd + 32]);
  float k1 = bf2f(qkv[mrow + 1024 + hd]);
  float k2 = bf2f(qkv[mrow + 1024 + hd + 32]);
  // inv = 10000^(-d/32) = exp2(-d * log2(10000)/32); device exp2f -> v_exp_f32 path
  float inv = exp2f(-(float)d * 0.41524101186092029f);
  float ang = (float)t * inv;
  float s, c;
  __sincosf(ang, &s, &c);
  size_t orow = ((size_t)((b * NHEAD + h) * T_SEQ + t)) * 64 + d;
  Qb[orow]      = f2bf(q1 * c - q2 * s);
  Qb[orow + 32] = f2bf(q2 * c + q1 * s);
  Kb[orow]      = f2bf(k1 * c - k2 * s);
  Kb[orow + 32] = f2bf(k2 * c + k1 * s);
}

// ---------------- V transpose: qkv slice -> Vt (B,H,Dh,T) bf16 ----------------
__global__ __launch_bounds__(256) void v_trans(const u16* __restrict__ qkv,
                                               u16* __restrict__ Vt) {
  __shared__ u16 tile[64][72];
  const int t0 = blockIdx.x * 64;
  const int bh = blockIdx.y;
  const int b = bh >> 4, h = bh & 15;
  const int tid = threadIdx.x;
#pragma unroll
  for (int it = 0; it < 16; it++) {
    int idx = it * 256 + tid;
    int tl = idx >> 6, d = idx & 63;
    tile[tl][d] = qkv[((size_t)(b * T_SEQ + t0 + tl)) * 3072 + 2048 + h * 64 + d];
  }
  __syncthreads();
#pragma unroll
  for (int it = 0; it < 16; it++) {
    int idx = it * 256 + tid;
    int d = idx >> 6, tl = idx & 63;
    Vt[((size_t)bh * 64 + d) * T_SEQ + t0 + tl] = tile[tl][d];
  }
}

// ---------------- windowed flash attention (LDS-staged, dbuf, swizzled) ----
__device__ __forceinline__ void stage_kv(const u16* __restrict__ Kh,
                                         const u16* __restrict__ Vh, int k0,
                                         u16* lk, u16* lv, int tid) {
  const int wave = tid >> 6;
#pragma unroll
  for (int p = 0; p < 2; p++) {
    int c = p * 256 + tid;
    int row = c >> 3;
    int col = ((c & 7) ^ (row & 7)) * 8;  // pre-swizzled source column
    g2l16(Kh + (size_t)(k0 + row) * 64 + col, lk + p * 2048 + wave * 512);
    g2l16(Vh + (size_t)row * T_SEQ + k0 + col, lv + p * 2048 + wave * 512);
  }
}

// grid: 1024 blocks (XCD-remapped), 4 waves; wave w owns q rows [qt*64+w*16,+16)
__global__ __launch_bounds__(256) void attn_k(const u16* __restrict__ Qb,
                                              const u16* __restrict__ Kb,
                                              const u16* __restrict__ Vt,
                                              u16* __restrict__ Ob) {
  const int bid = blockIdx.x;
  const int owned = (bid & 7) * 128 + (bid >> 3);
  const int qt = owned & 31;
  const int bh = owned >> 5;

  const int tid = threadIdx.x, lane = tid & 63, w = tid >> 6;
  const int r = lane & 15, g = lane >> 4;
  const int q0 = qt * 64;
  const u16* Qh = Qb + (size_t)bh * T_SEQ * 64;
  const u16* Kh = Kb + (size_t)bh * T_SEQ * 64;
  const u16* Vh = Vt + (size_t)bh * 64 * T_SEQ;

  __shared__ u16 lK[2][64 * 64];
  __shared__ u16 lV[2][64 * 64];
  __shared__ u16 p_lds[4][16][72];

  short8 aq[2];
#pragma unroll
  for (int kk = 0; kk < 2; kk++)
    aq[kk] = *reinterpret_cast<const short8*>(
        &Qh[(size_t)(q0 + w * 16 + r) * 64 + kk * 32 + g * 8]);

  f32x4 o[4];
#pragma unroll
  for (int n = 0; n < 4; n++) o[n] = (f32x4){0.f, 0.f, 0.f, 0.f};
  float mrun[4], lrun[4];
#pragma unroll
  for (int j = 0; j < 4; j++) { mrun[j] = -1e30f; lrun[j] = 0.f; }

  const int ktlo = (qt >= 4) ? (qt - 4) : 0;
  stage_kv(Kh, Vh, qt * 64, lK[0], lV[0], tid);
  __syncthreads();  // vmcnt(0) drain: tile qt resident
  int buf = 0;

  for (int kt = qt; kt >= ktlo; kt--) {
    const int k0 = kt * 64;
    if (kt > ktlo)
      stage_kv(Kh, Vh, (kt - 1) * 64, lK[buf ^ 1], lV[buf ^ 1], tid);

    const u16* lk = lK[buf];
    const u16* lv = lV[buf];
    const int sw = (r & 7) * 8;

    f32x4 s[4];
#pragma unroll
    for (int n = 0; n < 4; n++) {
      f32x4 sn = (f32x4){0.f, 0.f, 0.f, 0.f};
#pragma unroll
      for (int kk = 0; kk < 2; kk++) {
        short8 bk = *reinterpret_cast<const short8*>(
            &lk[(n * 16 + r) * 64 + ((kk * 32 + g * 8) ^ sw)]);
        sn = __builtin_amdgcn_mfma_f32_16x16x32_bf16(aq[kk], bk, sn, 0, 0, 0);
      }
      s[n] = sn;
    }
    float rmax[4] = {-1e30f, -1e30f, -1e30f, -1e30f};
#pragma unroll
    for (int n = 0; n < 4; n++) {
      const int k = k0 + n * 16 + r;
#pragma unroll
      for (int j = 0; j < 4; j++) {
        const int q = q0 + w * 16 + g * 4 + j;
        float v = s[n][j] * 0.125f;
        bool ok = (k <= q) && (q - k < WIN);
        v = ok ? v : -1e30f;
        s[n][j] = v;
        rmax[j] = fmaxf(rmax[j], v);
      }
    }
#pragma unroll
    for (int off = 1; off < 16; off <<= 1)
#pragma unroll
      for (int j = 0; j < 4; j++) rmax[j] = fmaxf(rmax[j], __shfl_xor(rmax[j], off));

    float scl[4];
#pragma unroll
    for (int j = 0; j < 4; j++) {
      float mn = fmaxf(mrun[j], rmax[j]);
      scl[j] = __expf(mrun[j] - mn);
      mrun[j] = mn;
    }
    float rsum[4] = {0.f, 0.f, 0.f, 0.f};
#pragma unroll
    for (int n = 0; n < 4; n++)
#pragma unroll
      for (int j = 0; j < 4; j++) {
        float p = __expf(s[n][j] - mrun[j]);
        s[n][j] = p;
        rsum[j] += p;
      }
#pragma unroll
    for (int off = 1; off < 16; off <<= 1)
#pragma unroll
      for (int j = 0; j < 4; j++) rsum[j] += __shfl_xor(rsum[j], off);
#pragma unroll
    for (int j = 0; j < 4; j++) lrun[j] = lrun[j] * scl[j] + rsum[j];
#pragma unroll
    for (int n = 0; n < 4; n++)
#pragma unroll
      for (int j = 0; j < 4; j++) o[n][j] *= scl[j];

#pragma unroll
    for (int n = 0; n < 4; n++)
#pragma unroll
      for (int j = 0; j < 4; j++) p_lds[w][g * 4 + j][n * 16 + r] = f2bf(s[n][j]);
#pragma unroll
    for (int kk = 0; kk < 2; kk++) {
      short8 ap = *reinterpret_cast<const short8*>(&p_lds[w][r][kk * 32 + g * 8]);
#pragma unroll
      for (int n = 0; n < 4; n++) {
        short8 bv = *reinterpret_cast<const short8*>(
            &lv[(n * 16 + r) * 64 + ((kk * 32 + g * 8) ^ sw)]);
        o[n] = __builtin_amdgcn_mfma_f32_16x16x32_bf16(ap, bv, o[n], 0, 0, 0);
      }
    }
    __syncthreads();
    buf ^= 1;
  }

  const int b = bh >> 4, h = bh & 15;
#pragma unroll
  for (int n = 0; n < 4; n++)
#pragma unroll
    for (int j = 0; j < 4; j++) {
      const int q = q0 + w * 16 + g * 4 + j;
      size_t off = ((size_t)(b * T_SEQ + q)) * 1024 + h * 64 + n * 16 + r;
      Ob[off] = f2bf(o[n][j] / lrun[j]);
    }
}

// ---------------- launch ----------------
extern "C" void kernel_launch(void* const* d_in, const int* in_sizes, int n_in,
                              void* d_out, int out_size, void* d_ws, size_t ws_size,
                              hipStream_t stream) {
  const float* x = (const float*)d_in[0];
  const float* w_qkv = (const float*)d_in[1];
  const float* w_out = (const float*)d_in[2];
  float* out = (float*)d_out;
  char* ws = (char*)d_ws;

  // ws layout (stream-ordered aliasing):
  u16* xb    = (u16*)(ws + 0);          // 8 MB  (dead after gemm1)
  u16* wqkvb = (u16*)(ws + 8388608);    // 6 MB  (dead after gemm1)
  u16* qkvb  = (u16*)(ws + 16777216);   // 24 MB (dead after rope+vtrans)
  u16* Qb    = (u16*)(ws + 0);          // 8 MB  (reuses xb)
  u16* Kb    = (u16*)(ws + 8388608);    // 8 MB  (reuses wqkvb region)
  u16* Vt    = (u16*)(ws + 41943040);   // 8 MB
  u16* woutb = (u16*)(ws + 50331648);   // 2 MB
  u16* Ob    = (u16*)(ws + 16777216);   // 8 MB  (reuses qkvb)

  cast_bf16_k<<<4096, 256, 0, stream>>>(x, xb, 1048576);
  cast_bf16_k<<<3072, 256, 0, stream>>>(w_qkv, wqkvb, 786432);
  cast_bf16_k<<<1024, 256, 0, stream>>>(w_out, woutb, 262144);

  // 1D grids for XCD remap: (M/128)*(N/128) blocks, N/128 divisible by 8
  gemm_nt<u16><<<768, 256, 0, stream>>>(xb, wqkvb, qkvb, 4096, 3072, 1024);

  rope_qk<<<8192, 256, 0, stream>>>(qkvb, Qb, Kb);
  v_trans<<<dim3(32, 32), 256, 0, stream>>>(qkvb, Vt);

  attn_k<<<1024, 256, 0, stream>>>(Qb, Kb, Vt, Ob);

  gemm_nt<float><<<256, 256, 0, stream>>>(Ob, woutb, out, 4096, 1024, 1024);
}

// Round 12
// 171.936 us; speedup vs baseline: 1.0681x; 1.0681x over previous
//
#include <hip/hip_runtime.h>
#include <stdint.h>
#include <math.h>

#define T_SEQ 2048
#define NHEAD 16
#define WIN 256

typedef unsigned short u16;
typedef __attribute__((ext_vector_type(8))) short short8;
typedef __attribute__((ext_vector_type(4))) float f32x4;

typedef const __attribute__((address_space(1))) void* gas_ptr;
typedef __attribute__((address_space(3))) void* las_ptr;

__device__ __forceinline__ u16 f2bf(float f) {
  uint32_t u = __builtin_bit_cast(uint32_t, f);
  u += 0x7fffu + ((u >> 16) & 1u);
  return (u16)(u >> 16);
}
__device__ __forceinline__ float bf2f(u16 v) {
  return __builtin_bit_cast(float, ((uint32_t)v) << 16);
}
__device__ __forceinline__ void g2l16(const u16* g, u16* l) {
  __builtin_amdgcn_global_load_lds((gas_ptr)g, (las_ptr)l, 16, 0, 0);
}

// ---------------- fp32 -> bf16 cast (vectorized) ----------------
__global__ __launch_bounds__(256) void cast_bf16_k(const float* __restrict__ in,
                                                   u16* __restrict__ out, int n4) {
  int i = blockIdx.x * 256 + threadIdx.x;
  if (i >= n4) return;
  const float4 v = reinterpret_cast<const float4*>(in)[i];
  union { u16 h[4]; uint64_t q; } o;
  o.h[0] = f2bf(v.x); o.h[1] = f2bf(v.y); o.h[2] = f2bf(v.z); o.h[3] = f2bf(v.w);
  reinterpret_cast<uint64_t*>(out)[i] = o.q;
}

// ---------------- NT GEMM: C[M][N] = A[M][K] * B[N][K]^T ----------------
// 128x128 tile, BK=32, 4 waves (2x2), 4x4 16x16x32 MFMA frags per wave.
// K-loop: 3-buffer LDS pipeline (HW-verified round 10), tile t+2 staged at
// iter t, counted vmcnt + raw barrier.
// MODE 0: plain store to C (fp32 or bf16).
// MODE 1: fused qkv epilogue — writes RoPE'd Q,K to (b,h,t,d) bf16 and
//         transposed V to (b,h,d,t) bf16 directly from acc (kills the
//         rope_qk and v_trans passes; ~17 us of pure data movement).
template <int MODE, typename OUT_T>
__global__ __launch_bounds__(256) void gemm_nt(const u16* __restrict__ A,
                                               const u16* __restrict__ B,
                                               OUT_T* __restrict__ C,
                                               u16* __restrict__ Qb,
                                               u16* __restrict__ Kb,
                                               u16* __restrict__ Vt,
                                               int M, int N, int K) {
  __shared__ u16 lA[3][4096];  // 3 x 8KB per operand = 48KB total
  __shared__ u16 lB[3][4096];
  const int tid = threadIdx.x;
  const int lane = tid & 63;
  const int wave = tid >> 6;
  const int r = lane & 15, g = lane >> 4;
  const int wr = wave >> 1, wc = wave & 1;

  // XCD remap: bid%8 = xcd; xcd owns bn in [xcd*bnpx, (xcd+1)*bnpx), bm 0..
  const int nbn = N >> 7;            // 128-wide tiles; nbn % 8 == 0 required
  const int bnpx = nbn >> 3;
  const int bid = blockIdx.x;
  const int xcd = bid & 7, ii = bid >> 3;
  const int bn = xcd * bnpx + (ii % bnpx);
  const int bm = ii / bnpx;

  const u16* Abase = A + (size_t)bm * 128 * K;
  const u16* Bbase = B + (size_t)bn * 128 * K;

  f32x4 acc[4][4];
#pragma unroll
  for (int m = 0; m < 4; m++)
#pragma unroll
    for (int n = 0; n < 4; n++) acc[m][n] = (f32x4){0.f, 0.f, 0.f, 0.f};

  const int c0 = tid, c1 = 256 + tid;
  const int row0 = c0 >> 2, row1 = c1 >> 2;
  const int sw0 = ((c0 & 3) ^ (row0 & 3)) * 8;
  const int sw1 = ((c1 & 3) ^ (row1 & 3)) * 8;
  const int ldsb = wave * 512;

  auto stage = [&](int k0, int b) {  // 4 global_load_lds per wave
    g2l16(Abase + (size_t)row0 * K + k0 + sw0, &lA[b][ldsb]);
    g2l16(Abase + (size_t)row1 * K + k0 + sw1, &lA[b][2048 + ldsb]);
    g2l16(Bbase + (size_t)row0 * K + k0 + sw0, &lB[b][ldsb]);
    g2l16(Bbase + (size_t)row1 * K + k0 + sw1, &lB[b][2048 + ldsb]);
  };

  const int nt = K >> 5;
  stage(0, 0);
  if (nt > 1) stage(32, 1);
  int cur = 0, pre = 2;

  const int rsw = (r & 3);
  for (int t = 0; t < nt; ++t) {
    if (t + 1 < nt) asm volatile("s_waitcnt vmcnt(4)" ::: "memory");
    else            asm volatile("s_waitcnt vmcnt(0)" ::: "memory");
    __builtin_amdgcn_s_barrier();
    if (t + 2 < nt) stage((t + 2) * 32, pre);

    const u16* la = lA[cur];
    const u16* lb = lB[cur];
    short8 af[4], bfr[4];
#pragma unroll
    for (int m = 0; m < 4; m++)
      af[m] = *reinterpret_cast<const short8*>(
          &la[(wr * 64 + m * 16 + r) * 32 + ((g ^ rsw) * 8)]);
#pragma unroll
    for (int n = 0; n < 4; n++)
      bfr[n] = *reinterpret_cast<const short8*>(
          &lb[(wc * 64 + n * 16 + r) * 32 + ((g ^ rsw) * 8)]);
#pragma unroll
    for (int m = 0; m < 4; m++)
#pragma unroll
      for (int n = 0; n < 4; n++)
        acc[m][n] = __builtin_amdgcn_mfma_f32_16x16x32_bf16(af[m], bfr[n], acc[m][n], 0, 0, 0);
    asm volatile("s_waitcnt lgkmcnt(0)" ::: "memory");
    cur = (cur == 2) ? 0 : cur + 1;
    pre = (pre == 2) ? 0 : pre + 1;
  }

  if constexpr (MODE == 0) {
#pragma unroll
    for (int m = 0; m < 4; m++) {
      const int row = bm * 128 + wr * 64 + m * 16 + g * 4;
#pragma unroll
      for (int n = 0; n < 4; n++) {
        const int col = bn * 128 + wc * 64 + n * 16 + r;
#pragma unroll
        for (int j = 0; j < 4; j++) {
          float v = acc[m][n][j];
          if constexpr (sizeof(OUT_T) == 2)
            C[(size_t)(row + j) * N + col] = f2bf(v);
          else
            C[(size_t)(row + j) * N + col] = v;
        }
      }
    }
  } else {
    // Fused qkv epilogue. Per block: region = bn>>3 (0=Q,1=K,2=V), batch
    // b = bm>>4, t0 = (bm&15)*128. Per wave: head h = (bn&7)*2 + wc.
    const int reg = bn >> 3;
    const int b = bm >> 4;
    const int h = ((bn & 7) << 1) + wc;
    const int bh = b * NHEAD + h;
    const int t0 = ((bm & 15) << 7) + wr * 64;

    if (reg == 2) {
      // V: Vt[(bh*64 + d)*T_SEQ + t], d = n*16 + r; j-consecutive t -> 8B runs
      u16* vb = Vt + (size_t)bh * 64 * T_SEQ;
#pragma unroll
      for (int n = 0; n < 4; n++) {
        const int d = n * 16 + r;
#pragma unroll
        for (int m = 0; m < 4; m++) {
          const int t = t0 + m * 16 + g * 4;
#pragma unroll
          for (int j = 0; j < 4; j++)
            vb[(size_t)d * T_SEQ + t + j] = f2bf(acc[m][n][j]);
        }
      }
    } else {
      // Q/K with RoPE: pairs (d, d+32) = (acc[m][n], acc[m][n+2]), n in {0,1}
      u16* qk = (reg == 0 ? Qb : Kb) + (size_t)bh * T_SEQ * 64;
#pragma unroll
      for (int n = 0; n < 2; n++) {
        const int d = n * 16 + r;  // in [0,32)
        const float inv = exp2f(-(float)d * 0.41524101186092029f);
#pragma unroll
        for (int m = 0; m < 4; m++) {
          const int tb = t0 + m * 16 + g * 4;
#pragma unroll
          for (int j = 0; j < 4; j++) {
            const int t = tb + j;
            float s, c;
            __sincosf((float)t * inv, &s, &c);
            const float x1 = acc[m][n][j], x2 = acc[m][n + 2][j];
            qk[(size_t)t * 64 + d]      = f2bf(x1 * c - x2 * s);
            qk[(size_t)t * 64 + d + 32] = f2bf(x2 * c + x1 * s);
          }
        }
      }
    }
  }
}

// ---------------- windowed flash attention (LDS-staged, dbuf, swizzled) ----
__device__ __forceinline__ void stage_kv(const u16* __restrict__ Kh,
                                         const u16* __restrict__ Vh, int k0,
                                         u16* lk, u16* lv, int tid) {
  const int wave = tid >> 6;
#pragma unroll
  for (int p = 0; p < 2; p++) {
    int c = p * 256 + tid;
    int row = c >> 3;
    int col = ((c & 7) ^ (row & 7)) * 8;  // pre-swizzled source column
    g2l16(Kh + (size_t)(k0 + row) * 64 + col, lk + p * 2048 + wave * 512);
    g2l16(Vh + (size_t)row * T_SEQ + k0 + col, lv + p * 2048 + wave * 512);
  }
}

// grid: 1024 blocks (XCD-remapped), 4 waves; wave w owns q rows [qt*64+w*16,+16)
__global__ __launch_bounds__(256) void attn_k(const u16* __restrict__ Qb,
                                              const u16* __restrict__ Kb,
                                              const u16* __restrict__ Vt,
                                              u16* __restrict__ Ob) {
  const int bid = blockIdx.x;
  const int owned = (bid & 7) * 128 + (bid >> 3);
  const int qt = owned & 31;
  const int bh = owned >> 5;

  const int tid = threadIdx.x, lane = tid & 63, w = tid >> 6;
  const int r = lane & 15, g = lane >> 4;
  const int q0 = qt * 64;
  const u16* Qh = Qb + (size_t)bh * T_SEQ * 64;
  const u16* Kh = Kb + (size_t)bh * T_SEQ * 64;
  const u16* Vh = Vt + (size_t)bh * 64 * T_SEQ;

  __shared__ u16 lK[2][64 * 64];
  __shared__ u16 lV[2][64 * 64];
  __shared__ u16 p_lds[4][16][72];

  short8 aq[2];
#pragma unroll
  for (int kk = 0; kk < 2; kk++)
    aq[kk] = *reinterpret_cast<const short8*>(
        &Qh[(size_t)(q0 + w * 16 + r) * 64 + kk * 32 + g * 8]);

  f32x4 o[4];
#pragma unroll
  for (int n = 0; n < 4; n++) o[n] = (f32x4){0.f, 0.f, 0.f, 0.f};
  float mrun[4], lrun[4];
#pragma unroll
  for (int j = 0; j < 4; j++) { mrun[j] = -1e30f; lrun[j] = 0.f; }

  const int ktlo = (qt >= 4) ? (qt - 4) : 0;
  stage_kv(Kh, Vh, qt * 64, lK[0], lV[0], tid);
  __syncthreads();  // vmcnt(0) drain: tile qt resident
  int buf = 0;

  for (int kt = qt; kt >= ktlo; kt--) {
    const int k0 = kt * 64;
    if (kt > ktlo)
      stage_kv(Kh, Vh, (kt - 1) * 64, lK[buf ^ 1], lV[buf ^ 1], tid);

    const u16* lk = lK[buf];
    const u16* lv = lV[buf];
    const int sw = (r & 7) * 8;

    f32x4 s[4];
#pragma unroll
    for (int n = 0; n < 4; n++) {
      f32x4 sn = (f32x4){0.f, 0.f, 0.f, 0.f};
#pragma unroll
      for (int kk = 0; kk < 2; kk++) {
        short8 bk = *reinterpret_cast<const short8*>(
            &lk[(n * 16 + r) * 64 + ((kk * 32 + g * 8) ^ sw)]);
        sn = __builtin_amdgcn_mfma_f32_16x16x32_bf16(aq[kk], bk, sn, 0, 0, 0);
      }
      s[n] = sn;
    }
    float rmax[4] = {-1e30f, -1e30f, -1e30f, -1e30f};
#pragma unroll
    for (int n = 0; n < 4; n++) {
      const int k = k0 + n * 16 + r;
#pragma unroll
      for (int j = 0; j < 4; j++) {
        const int q = q0 + w * 16 + g * 4 + j;
        float v = s[n][j] * 0.125f;
        bool ok = (k <= q) && (q - k < WIN);
        v = ok ? v : -1e30f;
        s[n][j] = v;
        rmax[j] = fmaxf(rmax[j], v);
      }
    }
#pragma unroll
    for (int off = 1; off < 16; off <<= 1)
#pragma unroll
      for (int j = 0; j < 4; j++) rmax[j] = fmaxf(rmax[j], __shfl_xor(rmax[j], off));

    float scl[4];
#pragma unroll
    for (int j = 0; j < 4; j++) {
      float mn = fmaxf(mrun[j], rmax[j]);
      scl[j] = __expf(mrun[j] - mn);
      mrun[j] = mn;
    }
    float rsum[4] = {0.f, 0.f, 0.f, 0.f};
#pragma unroll
    for (int n = 0; n < 4; n++)
#pragma unroll
      for (int j = 0; j < 4; j++) {
        float p = __expf(s[n][j] - mrun[j]);
        s[n][j] = p;
        rsum[j] += p;
      }
#pragma unroll
    for (int off = 1; off < 16; off <<= 1)
#pragma unroll
      for (int j = 0; j < 4; j++) rsum[j] += __shfl_xor(rsum[j], off);
#pragma unroll
    for (int j = 0; j < 4; j++) lrun[j] = lrun[j] * scl[j] + rsum[j];
#pragma unroll
    for (int n = 0; n < 4; n++)
#pragma unroll
      for (int j = 0; j < 4; j++) o[n][j] *= scl[j];

#pragma unroll
    for (int n = 0; n < 4; n++)
#pragma unroll
      for (int j = 0; j < 4; j++) p_lds[w][g * 4 + j][n * 16 + r] = f2bf(s[n][j]);
#pragma unroll
    for (int kk = 0; kk < 2; kk++) {
      short8 ap = *reinterpret_cast<const short8*>(&p_lds[w][r][kk * 32 + g * 8]);
#pragma unroll
      for (int n = 0; n < 4; n++) {
        short8 bv = *reinterpret_cast<const short8*>(
            &lv[(n * 16 + r) * 64 + ((kk * 32 + g * 8) ^ sw)]);
        o[n] = __builtin_amdgcn_mfma_f32_16x16x32_bf16(ap, bv, o[n], 0, 0, 0);
      }
    }
    __syncthreads();
    buf ^= 1;
  }

  const int b = bh >> 4, h = bh & 15;
#pragma unroll
  for (int n = 0; n < 4; n++)
#pragma unroll
    for (int j = 0; j < 4; j++) {
      const int q = q0 + w * 16 + g * 4 + j;
      size_t off = ((size_t)(b * T_SEQ + q)) * 1024 + h * 64 + n * 16 + r;
      Ob[off] = f2bf(o[n][j] / lrun[j]);
    }
}

// ---------------- launch ----------------
extern "C" void kernel_launch(void* const* d_in, const int* in_sizes, int n_in,
                              void* d_out, int out_size, void* d_ws, size_t ws_size,
                              hipStream_t stream) {
  const float* x = (const float*)d_in[0];
  const float* w_qkv = (const float*)d_in[1];
  const float* w_out = (const float*)d_in[2];
  float* out = (float*)d_out;
  char* ws = (char*)d_ws;

  // ws layout — fully disjoint (gemm1 writes Q/K/Vt while reading xb, so no
  // aliasing allowed): total 52 MB of 256 MB.
  u16* xb    = (u16*)(ws + 0);          //  8 MB
  u16* wqkvb = (u16*)(ws + 8388608);    //  6 MB
  u16* Qb    = (u16*)(ws + 16777216);   //  8 MB
  u16* Kb    = (u16*)(ws + 25165824);   //  8 MB
  u16* Vt    = (u16*)(ws + 33554432);   //  8 MB
  u16* Ob    = (u16*)(ws + 41943040);   //  8 MB
  u16* woutb = (u16*)(ws + 50331648);   //  2 MB

  cast_bf16_k<<<4096, 256, 0, stream>>>(x, xb, 1048576);
  cast_bf16_k<<<3072, 256, 0, stream>>>(w_qkv, wqkvb, 786432);
  cast_bf16_k<<<1024, 256, 0, stream>>>(w_out, woutb, 262144);

  // gemm1 fused: writes RoPE'd Q,K and transposed V directly (no qkv tensor)
  gemm_nt<1, u16><<<768, 256, 0, stream>>>(xb, wqkvb, (u16*)nullptr,
                                           Qb, Kb, Vt, 4096, 3072, 1024);

  attn_k<<<1024, 256, 0, stream>>>(Qb, Kb, Vt, Ob);

  gemm_nt<0, float><<<256, 256, 0, stream>>>(Ob, woutb, out,
                                             nullptr, nullptr, nullptr,
                                             4096, 1024, 1024);
}